// Round 3
// baseline (630.600 us; speedup 1.0000x reference)
//
#include <hip/hip_runtime.h>
#include <hip/hip_bf16.h>

// EncoderCell, bf16-MFMA, round 3.
//   gemm_bf16: 128x128 tile, m97-style gl_lds16 staging; lda/ldb + split-K via z
//              (bias only on z==0; partials summed in ln_res).
//   attn_mfma: S^T = K.Q^T formulation; all LDS tiles padded to stride 72
//              (2-way alias only); explicit staged K/V with reg pipeline;
//              vectorized mask loads; PV as O^T = V^T.P^T; packed stores.
//   ln_res:    mode 0: out=LN(a+a2)+r ; mode 1: out=LN(a+a2+r). a2 nullable.
// ws (MiB): [0,24) qb|kb|vb -> vhT|zb|xb ; [24,30) WqkvT ; [30,32) WdT ;
//   [32,40) W1T ; [40,48) W2T ; [48,72) qh|kh|vh ; after attn: zd0 [48,64),
//   zd1 [64,80) ; x [80,96) ; h1 [96,128) ; y0/y1 reuse [48,80).  = 128 MiB.

#define SEQ 2048
#define DM  1024
#define LNEPS 1e-5f

typedef __attribute__((ext_vector_type(8))) short bf16x8;
typedef __attribute__((ext_vector_type(4))) float f32x4;

#define GAS __attribute__((address_space(1)))
#define LAS __attribute__((address_space(3)))

static __device__ __forceinline__ void gl_lds16(const unsigned short* g, unsigned short* l) {
    __builtin_amdgcn_global_load_lds((const GAS void*)g, (LAS void*)l, 16, 0, 0);
}

static __device__ __forceinline__ unsigned short f2bf(float f) {
    unsigned u = __builtin_bit_cast(unsigned, f);
    u += 0x7fffu + ((u >> 16) & 1u);   // RNE
    return (unsigned short)(u >> 16);
}

// ------------------------------------------------------------------
// C[M,N] (+= per-z slice) = A[M,Klen] @ Bt[N,Klen]^T.
// z-dim: batch or k-split via element offsets sA,sB,sC. bias only on z==0.
// ------------------------------------------------------------------
__global__ __launch_bounds__(256) void gemm_bf16(
    const unsigned short* __restrict__ A, const unsigned short* __restrict__ Bt,
    float* __restrict__ Cf, unsigned short* __restrict__ Cb,
    int M, int N, int Klen, int lda, int ldb,
    size_t sA, size_t sB, size_t sC,
    const float* __restrict__ bias, int ep)
{
    __shared__ unsigned short As[128 * 32];
    __shared__ unsigned short Bs[128 * 32];

    const int t = threadIdx.x, lane = t & 63, w = t >> 6;
    const int wm = w >> 1, wn = w & 1;
    const int m0 = blockIdx.y * 128, n0 = blockIdx.x * 128;
    A  += (size_t)blockIdx.z * sA;
    Bt += (size_t)blockIdx.z * sB;
    const size_t cbase = (size_t)blockIdx.z * sC;
    const int l15 = lane & 15, l16 = lane >> 4;
    const int ar = lane >> 2, ac = (lane & 3) * 8;

    f32x4 acc[4][4];
    #pragma unroll
    for (int i = 0; i < 4; i++)
        #pragma unroll
        for (int j = 0; j < 4; j++)
            acc[i][j] = (f32x4){0.f, 0.f, 0.f, 0.f};

    for (int k0 = 0; k0 < Klen; k0 += 32) {
        __syncthreads();
        #pragma unroll
        for (int i = 0; i < 2; i++) {
            const int rg = w * 2 + i;
            gl_lds16(&A [(size_t)(m0 + rg * 16 + ar) * lda + k0 + ac], &As[rg * 512]);
            gl_lds16(&Bt[(size_t)(n0 + rg * 16 + ar) * ldb + k0 + ac], &Bs[rg * 512]);
        }
        __syncthreads();

        bf16x8 af[4], bfr[4];
        #pragma unroll
        for (int i = 0; i < 4; i++) {
            af[i]  = *(const bf16x8*)&As[(wm * 64 + i * 16 + l15) * 32 + l16 * 8];
            bfr[i] = *(const bf16x8*)&Bs[(wn * 64 + i * 16 + l15) * 32 + l16 * 8];
        }
        #pragma unroll
        for (int mi = 0; mi < 4; mi++)
            #pragma unroll
            for (int ni = 0; ni < 4; ni++)
                acc[mi][ni] = __builtin_amdgcn_mfma_f32_16x16x32_bf16(
                    af[mi], bfr[ni], acc[mi][ni], 0, 0, 0);
    }

    #pragma unroll
    for (int ni = 0; ni < 4; ni++) {
        const int col = n0 + wn * 64 + ni * 16 + l15;
        const float bv = (ep && blockIdx.z == 0) ? bias[col] : 0.f;
        #pragma unroll
        for (int mi = 0; mi < 4; mi++) {
            #pragma unroll
            for (int r = 0; r < 4; r++) {
                const int row = m0 + wm * 64 + mi * 16 + l16 * 4 + r;
                float vv = acc[mi][ni][r] + bv;
                if (ep == 2) vv = fmaxf(vv, 0.f);
                if (Cf) Cf[cbase + (size_t)row * N + col] = vv;
                else    Cb[cbase + (size_t)row * N + col] = f2bf(vv);
            }
        }
    }
}

// ------------------------------------------------------------------
// Flash attention, S^T formulation. grid = 1024; decode: qt=bid>>5 (mask L2 reuse),
// h=bid&15, b=(bid>>4)&1. Block: 64 q-rows; wave w owns q rows [w*16, w*16+16).
// Each lane handles ONE q-row (q = qr + l15) per tile; keys = ki*16 + l16*4 + r.
// ------------------------------------------------------------------
__global__ __launch_bounds__(256) void attn_mfma(
    const unsigned short* __restrict__ qh, const unsigned short* __restrict__ kh,
    const unsigned short* __restrict__ vhT, const float* __restrict__ mask,
    unsigned short* __restrict__ z)
{
    __shared__ unsigned short Qs[64 * 72];
    __shared__ unsigned short Ks[64 * 72];    // [key][d]
    __shared__ unsigned short Vst[64 * 72];   // [d][key]
    __shared__ unsigned short Ps[64 * 72];    // [q][key]

    const int t = threadIdx.x, lane = t & 63, w = t >> 6;
    const int bid = blockIdx.x;
    const int qt = bid >> 5, h = bid & 15, b = (bid >> 4) & 1;
    const int q0 = qt * 64, qr = w * 16;
    const int l15 = lane & 15, l16 = lane >> 4;
    const int sr = t >> 3, sc = (t & 7) * 8;   // staging: row, 8-short chunk

    // stage Q (padded) ---------------------------------------------------
    #pragma unroll
    for (int i = 0; i < 2; i++) {
        const int row = sr + i * 32;
        *(uint4*)&Qs[row * 72 + sc] =
            *(const uint4*)&qh[(size_t)(b * SEQ + q0 + row) * DM + h * 64 + sc];
    }
    __syncthreads();
    const bf16x8 bQ0 = *(const bf16x8*)&Qs[(qr + l15) * 72 + l16 * 8];
    const bf16x8 bQ1 = *(const bf16x8*)&Qs[(qr + l15) * 72 + 32 + l16 * 8];

    const size_t kbase = (size_t)b * SEQ * DM + h * 64;
    const size_t vbase = (size_t)((b * 16 + h) * 64) * SEQ;
    const float* mrow = mask + (size_t)(q0 + qr + l15) * SEQ;

    uint4 kreg[2], vreg[2];
    #pragma unroll
    for (int i = 0; i < 2; i++) {
        const int row = sr + i * 32;
        kreg[i] = *(const uint4*)&kh [kbase + (size_t)row * DM + sc];
        vreg[i] = *(const uint4*)&vhT[vbase + (size_t)row * SEQ + sc];
    }

    float m_i = -1e30f, l_i = 0.f;
    f32x4 o4[4];
    #pragma unroll
    for (int mi = 0; mi < 4; mi++) o4[mi] = (f32x4){0.f, 0.f, 0.f, 0.f};

    for (int kt = 0; kt < SEQ / 64; kt++) {
        const int k0 = kt * 64;
        __syncthreads();                       // prior-iter LDS reads done
        #pragma unroll
        for (int i = 0; i < 2; i++) {
            const int row = sr + i * 32;
            *(uint4*)&Ks [row * 72 + sc] = kreg[i];
            *(uint4*)&Vst[row * 72 + sc] = vreg[i];
        }
        __syncthreads();
        if (kt + 1 < SEQ / 64) {               // pipeline next tile
            const int k1 = k0 + 64;
            #pragma unroll
            for (int i = 0; i < 2; i++) {
                const int row = sr + i * 32;
                kreg[i] = *(const uint4*)&kh [kbase + (size_t)(k1 + row) * DM + sc];
                vreg[i] = *(const uint4*)&vhT[vbase + (size_t)row * SEQ + k1 + sc];
            }
        }

        // S^T = K . Q^T : row=key, col=q
        f32x4 s4[4];
        #pragma unroll
        for (int ki = 0; ki < 4; ki++) {
            const bf16x8 aK0 = *(const bf16x8*)&Ks[(ki * 16 + l15) * 72 + l16 * 8];
            const bf16x8 aK1 = *(const bf16x8*)&Ks[(ki * 16 + l15) * 72 + 32 + l16 * 8];
            f32x4 a0 = (f32x4){0.f, 0.f, 0.f, 0.f};
            a0 = __builtin_amdgcn_mfma_f32_16x16x32_bf16(aK0, bQ0, a0, 0, 0, 0);
            s4[ki] = __builtin_amdgcn_mfma_f32_16x16x32_bf16(aK1, bQ1, a0, 0, 0, 0);
        }

        // scale + mask (vectorized: 4 consecutive keys per acc reg)
        float sv[4][4];
        #pragma unroll
        for (int ki = 0; ki < 4; ki++) {
            const float4 mv = *(const float4*)&mrow[k0 + ki * 16 + l16 * 4];
            sv[ki][0] = s4[ki][0] * 0.125f + mv.x;
            sv[ki][1] = s4[ki][1] * 0.125f + mv.y;
            sv[ki][2] = s4[ki][2] * 0.125f + mv.z;
            sv[ki][3] = s4[ki][3] * 0.125f + mv.w;
        }

        // online softmax: lane owns q-row (qr+l15); reduce in-lane then over l16
        float rm = -1e30f;
        #pragma unroll
        for (int ki = 0; ki < 4; ki++)
            #pragma unroll
            for (int r = 0; r < 4; r++) rm = fmaxf(rm, sv[ki][r]);
        rm = fmaxf(rm, __shfl_xor(rm, 16));
        rm = fmaxf(rm, __shfl_xor(rm, 32));
        const float mnew  = fmaxf(m_i, rm);
        const float alpha = __expf(m_i - mnew);
        m_i = mnew;

        float ps = 0.f;
        #pragma unroll
        for (int ki = 0; ki < 4; ki++) {
            float p[4];
            #pragma unroll
            for (int r = 0; r < 4; r++) { p[r] = __expf(sv[ki][r] - mnew); ps += p[r]; }
            ushort4 pk;
            pk.x = f2bf(p[0]); pk.y = f2bf(p[1]); pk.z = f2bf(p[2]); pk.w = f2bf(p[3]);
            *(ushort4*)&Ps[(qr + l15) * 72 + ki * 16 + l16 * 4] = pk;
        }
        ps += __shfl_xor(ps, 16);
        ps += __shfl_xor(ps, 32);
        l_i = l_i * alpha + ps;
        #pragma unroll
        for (int mi = 0; mi < 4; mi++)
            #pragma unroll
            for (int r = 0; r < 4; r++) o4[mi][r] *= alpha;

        // O^T += V^T . P^T : A = Vst [d][key], B = Ps [q][key]
        const bf16x8 bP0 = *(const bf16x8*)&Ps[(qr + l15) * 72 + l16 * 8];
        const bf16x8 bP1 = *(const bf16x8*)&Ps[(qr + l15) * 72 + 32 + l16 * 8];
        #pragma unroll
        for (int mi = 0; mi < 4; mi++) {
            const bf16x8 aV0 = *(const bf16x8*)&Vst[(mi * 16 + l15) * 72 + l16 * 8];
            const bf16x8 aV1 = *(const bf16x8*)&Vst[(mi * 16 + l15) * 72 + 32 + l16 * 8];
            o4[mi] = __builtin_amdgcn_mfma_f32_16x16x32_bf16(aV0, bP0, o4[mi], 0, 0, 0);
            o4[mi] = __builtin_amdgcn_mfma_f32_16x16x32_bf16(aV1, bP1, o4[mi], 0, 0, 0);
        }
    }

    // write O: lane's col q = qr+l15, rows d = mi*16 + l16*4 + r (packed 8B)
    const float inv = 1.f / l_i;
    #pragma unroll
    for (int mi = 0; mi < 4; mi++) {
        ushort4 ok;
        ok.x = f2bf(o4[mi][0] * inv); ok.y = f2bf(o4[mi][1] * inv);
        ok.z = f2bf(o4[mi][2] * inv); ok.w = f2bf(o4[mi][3] * inv);
        *(ushort4*)&z[(size_t)(b * SEQ + q0 + qr + l15) * DM + h * 64 + mi * 16 + l16 * 4] = ok;
    }
}

// ------------------------------------------------------------------
__global__ __launch_bounds__(256) void cast3_bf16(
    const float* __restrict__ a0, const float* __restrict__ a1, const float* __restrict__ a2,
    unsigned short* __restrict__ out)
{
    const float* src = blockIdx.z == 0 ? a0 : (blockIdx.z == 1 ? a1 : a2);
    const size_t i = ((size_t)blockIdx.x * 256 + threadIdx.x) * 4;
    const float4 v = *(const float4*)&src[i];
    ushort4 o; o.x = f2bf(v.x); o.y = f2bf(v.y); o.z = f2bf(v.z); o.w = f2bf(v.w);
    *(ushort4*)&out[(size_t)blockIdx.z * ((size_t)SEQ * 2 * DM) + i] = o;
}

// W[K][N] fp32 -> Wt[N][K] bf16 ; grid (N/64, K/64)
__global__ __launch_bounds__(256) void transpose_cast(
    const float* __restrict__ W, unsigned short* __restrict__ Wt, int K, int N)
{
    __shared__ float ts[64][65];
    const int n0 = blockIdx.x * 64, k0 = blockIdx.y * 64;
    const int t = threadIdx.x, r = t >> 4, c4 = (t & 15) * 4;
    #pragma unroll
    for (int i = 0; i < 4; i++) {
        const float4 v = *(const float4*)&W[(size_t)(k0 + r + i * 16) * N + n0 + c4];
        ts[r + i * 16][c4 + 0] = v.x; ts[r + i * 16][c4 + 1] = v.y;
        ts[r + i * 16][c4 + 2] = v.z; ts[r + i * 16][c4 + 3] = v.w;
    }
    __syncthreads();
    #pragma unroll
    for (int i = 0; i < 4; i++) {
        const int n = r + i * 16;
        ushort4 o;
        o.x = f2bf(ts[c4 + 0][n]); o.y = f2bf(ts[c4 + 1][n]);
        o.z = f2bf(ts[c4 + 2][n]); o.w = f2bf(ts[c4 + 3][n]);
        *(ushort4*)&Wt[(size_t)(n0 + n) * K + k0 + c4] = o;
    }
}

// vh bf16 [B*S][DM] -> vhT bf16 [(b*16+h)*64 + d][SEQ] ; grid (S/64, H, B)
__global__ __launch_bounds__(256) void transpose_v(
    const unsigned short* __restrict__ vh, unsigned short* __restrict__ vhT)
{
    __shared__ unsigned short ts[64][80];
    const int s0 = blockIdx.x * 64, h = blockIdx.y, b = blockIdx.z;
    const int t = threadIdx.x, rr = t >> 3, c8 = (t & 7) * 8;
    #pragma unroll
    for (int i = 0; i < 2; i++) {
        const int srow = rr + i * 32;
        *(uint4*)&ts[srow][c8] = *(const uint4*)&vh[(size_t)(b * SEQ + s0 + srow) * DM + h * 64 + c8];
    }
    __syncthreads();
    #pragma unroll
    for (int i = 0; i < 2; i++) {
        const int dr = rr + i * 32;
        ushort4 ov0, ov1;
        ov0.x = ts[c8 + 0][dr]; ov0.y = ts[c8 + 1][dr];
        ov0.z = ts[c8 + 2][dr]; ov0.w = ts[c8 + 3][dr];
        ov1.x = ts[c8 + 4][dr]; ov1.y = ts[c8 + 5][dr];
        ov1.z = ts[c8 + 6][dr]; ov1.w = ts[c8 + 7][dr];
        *(ushort4*)&vhT[(size_t)((b * 16 + h) * 64 + dr) * SEQ + s0 + c8] = ov0;
        *(ushort4*)&vhT[(size_t)((b * 16 + h) * 64 + dr) * SEQ + s0 + c8 + 4] = ov1;
    }
}

// ------------------------------------------------------------------
// LN + residual with optional second partial input (split-K sum).
// mode 0: out = LN(a+a2)*g+be + r (+bf16 copy) ; mode 1: out = LN(a+a2+r)*g+be
// ------------------------------------------------------------------
__global__ __launch_bounds__(256) void ln_res(
    const float* __restrict__ a, const float* __restrict__ a2,
    const float* __restrict__ r,
    const float* __restrict__ g, const float* __restrict__ be,
    float* __restrict__ out, unsigned short* __restrict__ outb, int mode)
{
    __shared__ float redls[8];
    const int row = blockIdx.x, t = threadIdx.x;
    const size_t base = (size_t)row * DM;

    float vals[4], s = 0.f, sq = 0.f;
    #pragma unroll
    for (int i = 0; i < 4; i++) {
        const int c = t + 256 * i;
        float x = a[base + c];
        if (a2) x += a2[base + c];
        if (mode == 1) x += r[base + c];
        vals[i] = x; s += x; sq += x * x;
    }
    #pragma unroll
    for (int off = 32; off > 0; off >>= 1) { s += __shfl_down(s, off); sq += __shfl_down(sq, off); }
    if ((t & 63) == 0) { redls[t >> 6] = s; redls[4 + (t >> 6)] = sq; }
    __syncthreads();
    s  = redls[0] + redls[1] + redls[2] + redls[3];
    sq = redls[4] + redls[5] + redls[6] + redls[7];

    const float mu  = s * (1.f / 1024.f);
    const float var = sq * (1.f / 1024.f) - mu * mu;
    const float rs  = rsqrtf(var + LNEPS);
    #pragma unroll
    for (int i = 0; i < 4; i++) {
        const int c = t + 256 * i;
        float y = (vals[i] - mu) * rs * g[c] + be[c];
        if (mode == 0) y += r[base + c];
        out[base + c] = y;
        if (outb) outb[base + c] = f2bf(y);
    }
}

// ------------------------------------------------------------------
extern "C" void kernel_launch(void* const* d_in, const int* in_sizes, int n_in,
                              void* d_out, int out_size, void* d_ws, size_t ws_size,
                              hipStream_t stream)
{
    const float* q    = (const float*)d_in[0];
    const float* k    = (const float*)d_in[1];
    const float* v    = (const float*)d_in[2];
    const float* mask = (const float*)d_in[4];
    const float* Wq   = (const float*)d_in[5];
    const float* Wk   = (const float*)d_in[6];
    const float* Wv   = (const float*)d_in[7];
    const float* Wd   = (const float*)d_in[8];
    const float* W1   = (const float*)d_in[9];
    const float* b1   = (const float*)d_in[10];
    const float* W2   = (const float*)d_in[11];
    const float* b2   = (const float*)d_in[12];
    const float* g1   = (const float*)d_in[13];
    const float* be1  = (const float*)d_in[14];
    const float* g2   = (const float*)d_in[15];
    const float* be2  = (const float*)d_in[16];
    float* out = (float*)d_out;

    char* WS = (char*)d_ws;
    const size_t MiB = 1u << 20;
    const size_t ND  = (size_t)4096 * 1024;

    unsigned short* qb  = (unsigned short*)(WS + 0);          // 24 MiB qb|kb|vb
    unsigned short* vhT = (unsigned short*)(WS + 0);          //  8 MiB (reuse)
    unsigned short* zb  = (unsigned short*)(WS + 8 * MiB);    //  8 MiB (reuse)
    unsigned short* xb  = (unsigned short*)(WS + 16 * MiB);   //  8 MiB (reuse)
    unsigned short* Wqt = (unsigned short*)(WS + 24 * MiB);   //  6 MiB WqT|WkT|WvT
    unsigned short* Wdt = (unsigned short*)(WS + 30 * MiB);   //  2 MiB
    unsigned short* W1t = (unsigned short*)(WS + 32 * MiB);   //  8 MiB
    unsigned short* W2t = (unsigned short*)(WS + 40 * MiB);   //  8 MiB
    unsigned short* qh  = (unsigned short*)(WS + 48 * MiB);   // 24 MiB qh|kh|vh
    float*          zd0 = (float*)(WS + 48 * MiB);            // 16 MiB (reuse qh|kh)
    float*          zd1 = (float*)(WS + 64 * MiB);            // 16 MiB (reuse vh+)
    float*          x   = (float*)(WS + 80 * MiB);            // 16 MiB
    unsigned short* h1  = (unsigned short*)(WS + 96 * MiB);   // 32 MiB
    float*          y0  = (float*)(WS + 48 * MiB);            // reuse zd
    float*          y1  = (float*)(WS + 64 * MiB);

    unsigned short* kh = qh + ND;
    unsigned short* vh = qh + 2 * ND;

    const dim3 blk(256);

    cast3_bf16<<<dim3(4096, 1, 3), blk, 0, stream>>>(q, k, v, qb);
    transpose_cast<<<dim3(16, 16), blk, 0, stream>>>(Wq, Wqt,                   1024, 1024);
    transpose_cast<<<dim3(16, 16), blk, 0, stream>>>(Wk, Wqt + 1024 * 1024,     1024, 1024);
    transpose_cast<<<dim3(16, 16), blk, 0, stream>>>(Wv, Wqt + 2 * 1024 * 1024, 1024, 1024);
    transpose_cast<<<dim3(16, 16), blk, 0, stream>>>(Wd, Wdt, 1024, 1024);
    transpose_cast<<<dim3(64, 16), blk, 0, stream>>>(W1, W1t, 1024, 4096);
    transpose_cast<<<dim3(16, 64), blk, 0, stream>>>(W2, W2t, 4096, 1024);

    // QKV projections (z = batch of 3)
    gemm_bf16<<<dim3(8, 32, 3), blk, 0, stream>>>(qb, Wqt, nullptr, qh,
        4096, 1024, 1024, 1024, 1024, ND, (size_t)1024 * 1024, ND, nullptr, 0);

    transpose_v<<<dim3(32, 16, 2), blk, 0, stream>>>(vh, vhT);

    attn_mfma<<<dim3(1024), blk, 0, stream>>>(qh, kh, vhT, mask, zb);

    // out-proj, split-K x2 -> zd0/zd1
    gemm_bf16<<<dim3(8, 32, 2), blk, 0, stream>>>(zb, Wdt, zd0, nullptr,
        4096, 1024, 512, 1024, 1024, 512, 512, ND, nullptr, 0);

    // LN1: x = LN(zd0+zd1) + q
    ln_res<<<dim3(4096), blk, 0, stream>>>(zd0, zd1, q, g1, be1, x, xb, 0);

    // FFN
    gemm_bf16<<<dim3(32, 32, 1), blk, 0, stream>>>(xb, W1t, nullptr, h1,
        4096, 4096, 1024, 1024, 1024, 0, 0, 0, b1, 2);
    gemm_bf16<<<dim3(8, 32, 2), blk, 0, stream>>>(h1, W2t, y0, nullptr,
        4096, 1024, 2048, 4096, 4096, 2048, 2048, ND, b2, 1);

    // LN2: out = LN(y0+y1+x)
    ln_res<<<dim3(4096), blk, 0, stream>>>(y0, y1, x, g2, be2, out, nullptr, 1);
}

// Round 4
// 501.975 us; speedup vs baseline: 1.2562x; 1.2562x over previous
//
#include <hip/hip_runtime.h>
#include <hip/hip_bf16.h>

// EncoderCell, bf16-MFMA, round 4.
//   gemm_bf16: 128x128 tile, m97-style gl_lds16 staging; lda/ldb + split-K via z.
//   attn_mfma: S^T = K.Q^T; K/V/Q staged via gl_lds16 with XOR-chunk swizzle
//              (LDS row r holds 16B chunk c at slot c^(r&7) -> conflict-free b128
//              reads, no register pipeline -> no scratch spill). Ps stride-72.
//   ln_res:    mode 0: out=LN(a+a2)+r ; mode 1: out=LN(a+a2+r). a2 nullable.
// ws (MiB): [0,24) qb|kb|vb -> vhT|zb|xb ; [24,30) WqkvT ; [30,32) WdT ;
//   [32,40) W1T ; [40,48) W2T ; [48,72) qh|kh|vh ; zd0 [48,64), zd1 [64,80) ;
//   x [80,96) ; h1 [96,128) ; y0/y1 reuse [48,80).  = 128 MiB.

#define SEQ 2048
#define DM  1024
#define LNEPS 1e-5f

typedef __attribute__((ext_vector_type(8))) short bf16x8;
typedef __attribute__((ext_vector_type(4))) float f32x4;

#define GAS __attribute__((address_space(1)))
#define LAS __attribute__((address_space(3)))

static __device__ __forceinline__ void gl_lds16(const unsigned short* g, unsigned short* l) {
    __builtin_amdgcn_global_load_lds((const GAS void*)g, (LAS void*)l, 16, 0, 0);
}

static __device__ __forceinline__ unsigned short f2bf(float f) {
    unsigned u = __builtin_bit_cast(unsigned, f);
    u += 0x7fffu + ((u >> 16) & 1u);   // RNE
    return (unsigned short)(u >> 16);
}

// ------------------------------------------------------------------
// C[M,N] (per-z slice) = A[M,Klen] @ Bt[N,Klen]^T. bias only on z==0.
// ------------------------------------------------------------------
__global__ __launch_bounds__(256) void gemm_bf16(
    const unsigned short* __restrict__ A, const unsigned short* __restrict__ Bt,
    float* __restrict__ Cf, unsigned short* __restrict__ Cb,
    int M, int N, int Klen, int lda, int ldb,
    size_t sA, size_t sB, size_t sC,
    const float* __restrict__ bias, int ep)
{
    __shared__ unsigned short As[128 * 32];
    __shared__ unsigned short Bs[128 * 32];

    const int t = threadIdx.x, lane = t & 63, w = t >> 6;
    const int wm = w >> 1, wn = w & 1;
    const int m0 = blockIdx.y * 128, n0 = blockIdx.x * 128;
    A  += (size_t)blockIdx.z * sA;
    Bt += (size_t)blockIdx.z * sB;
    const size_t cbase = (size_t)blockIdx.z * sC;
    const int l15 = lane & 15, l16 = lane >> 4;
    const int ar = lane >> 2, ac = (lane & 3) * 8;

    f32x4 acc[4][4];
    #pragma unroll
    for (int i = 0; i < 4; i++)
        #pragma unroll
        for (int j = 0; j < 4; j++)
            acc[i][j] = (f32x4){0.f, 0.f, 0.f, 0.f};

    for (int k0 = 0; k0 < Klen; k0 += 32) {
        __syncthreads();
        #pragma unroll
        for (int i = 0; i < 2; i++) {
            const int rg = w * 2 + i;
            gl_lds16(&A [(size_t)(m0 + rg * 16 + ar) * lda + k0 + ac], &As[rg * 512]);
            gl_lds16(&Bt[(size_t)(n0 + rg * 16 + ar) * ldb + k0 + ac], &Bs[rg * 512]);
        }
        __syncthreads();

        bf16x8 af[4], bfr[4];
        #pragma unroll
        for (int i = 0; i < 4; i++) {
            af[i]  = *(const bf16x8*)&As[(wm * 64 + i * 16 + l15) * 32 + l16 * 8];
            bfr[i] = *(const bf16x8*)&Bs[(wn * 64 + i * 16 + l15) * 32 + l16 * 8];
        }
        #pragma unroll
        for (int mi = 0; mi < 4; mi++)
            #pragma unroll
            for (int ni = 0; ni < 4; ni++)
                acc[mi][ni] = __builtin_amdgcn_mfma_f32_16x16x32_bf16(
                    af[mi], bfr[ni], acc[mi][ni], 0, 0, 0);
    }

    #pragma unroll
    for (int ni = 0; ni < 4; ni++) {
        const int col = n0 + wn * 64 + ni * 16 + l15;
        const float bv = (ep && blockIdx.z == 0) ? bias[col] : 0.f;
        #pragma unroll
        for (int mi = 0; mi < 4; mi++) {
            #pragma unroll
            for (int r = 0; r < 4; r++) {
                const int row = m0 + wm * 64 + mi * 16 + l16 * 4 + r;
                float vv = acc[mi][ni][r] + bv;
                if (ep == 2) vv = fmaxf(vv, 0.f);
                if (Cf) Cf[cbase + (size_t)row * N + col] = vv;
                else    Cb[cbase + (size_t)row * N + col] = f2bf(vv);
            }
        }
    }
}

// ------------------------------------------------------------------
// Flash attention, S^T formulation, gl_lds16 staging + XOR chunk swizzle.
// grid = 1024; qt=bid>>5 (mask L2 reuse), h=bid&15, b=(bid>>4)&1.
// Wave w owns q rows [w*16, w*16+16); lane owns q-row qr+l15.
// ------------------------------------------------------------------
__global__ __launch_bounds__(256) void attn_mfma(
    const unsigned short* __restrict__ qh, const unsigned short* __restrict__ kh,
    const unsigned short* __restrict__ vhT, const float* __restrict__ mask,
    unsigned short* __restrict__ z)
{
    __shared__ unsigned short Qs[64 * 64];    // swizzled [row][chunk^(row&7)]
    __shared__ unsigned short Ks[64 * 64];    // swizzled, [key][d]
    __shared__ unsigned short Vst[64 * 64];   // swizzled, [d][key]
    __shared__ unsigned short Ps[64 * 72];    // [q][key], stride 72

    const int t = threadIdx.x, lane = t & 63, w = t >> 6;
    const int bid = blockIdx.x;
    const int qt = bid >> 5, h = bid & 15, b = (bid >> 4) & 1;
    const int q0 = qt * 64, qr = w * 16;
    const int l15 = lane & 15, l16 = lane >> 4;

    // staging geometry: wave-call rg covers rows rg*8..rg*8+7 (1 KiB);
    // lane: row-in-group lr, slot=lane&7; fetch global chunk slot^lr -> swizzle.
    const int lr = lane >> 3;
    const int gc = ((lane & 7) ^ lr) * 8;     // swizzled source chunk (shorts)

    const size_t qbase = (size_t)(b * SEQ + q0) * DM + h * 64;
    const size_t kbase = (size_t)(b * SEQ) * DM + h * 64;
    const size_t vbase = (size_t)((b * 16 + h) * 64) * SEQ;

    #pragma unroll
    for (int i = 0; i < 2; i++) {
        const int rg = w * 2 + i;
        gl_lds16(&qh[qbase + (size_t)(rg * 8 + lr) * DM + gc], &Qs[rg * 512]);
    }
    __syncthreads();

    // fragment-read swizzled chunk offsets for row r (r&7 == l15&7 always here)
    const int sw0 = ((l16    ) ^ (l15 & 7)) * 8;
    const int sw1 = ((l16 + 4) ^ (l15 & 7)) * 8;
    const bf16x8 bQ0 = *(const bf16x8*)&Qs[(qr + l15) * 64 + sw0];
    const bf16x8 bQ1 = *(const bf16x8*)&Qs[(qr + l15) * 64 + sw1];

    const float* mrow = mask + (size_t)(q0 + qr + l15) * SEQ;

    float m_i = -1e30f, l_i = 0.f;
    f32x4 o4[4];
    #pragma unroll
    for (int mi = 0; mi < 4; mi++) o4[mi] = (f32x4){0.f, 0.f, 0.f, 0.f};

    for (int kt = 0; kt < SEQ / 64; kt++) {
        const int k0 = kt * 64;
        __syncthreads();                       // prior-iter LDS reads done
        #pragma unroll
        for (int i = 0; i < 2; i++) {
            const int rg = w * 2 + i;
            gl_lds16(&kh [kbase + (size_t)(k0 + rg * 8 + lr) * DM + gc], &Ks[rg * 512]);
            gl_lds16(&vhT[vbase + (size_t)(rg * 8 + lr) * SEQ + k0 + gc], &Vst[rg * 512]);
        }
        __syncthreads();

        // S^T = K . Q^T : row=key, col=q
        f32x4 s4[4];
        #pragma unroll
        for (int ki = 0; ki < 4; ki++) {
            const int r = ki * 16 + l15;
            const bf16x8 aK0 = *(const bf16x8*)&Ks[r * 64 + sw0];
            const bf16x8 aK1 = *(const bf16x8*)&Ks[r * 64 + sw1];
            f32x4 a0 = (f32x4){0.f, 0.f, 0.f, 0.f};
            a0 = __builtin_amdgcn_mfma_f32_16x16x32_bf16(aK0, bQ0, a0, 0, 0, 0);
            s4[ki] = __builtin_amdgcn_mfma_f32_16x16x32_bf16(aK1, bQ1, a0, 0, 0, 0);
        }

        // scale + mask (4 consecutive keys per acc reg)
        float sv[4][4];
        #pragma unroll
        for (int ki = 0; ki < 4; ki++) {
            const float4 mv = *(const float4*)&mrow[k0 + ki * 16 + l16 * 4];
            sv[ki][0] = s4[ki][0] * 0.125f + mv.x;
            sv[ki][1] = s4[ki][1] * 0.125f + mv.y;
            sv[ki][2] = s4[ki][2] * 0.125f + mv.z;
            sv[ki][3] = s4[ki][3] * 0.125f + mv.w;
        }

        // online softmax: lane owns q-row; in-lane reduce + 2 shuffles
        float rm = -1e30f;
        #pragma unroll
        for (int ki = 0; ki < 4; ki++)
            #pragma unroll
            for (int r = 0; r < 4; r++) rm = fmaxf(rm, sv[ki][r]);
        rm = fmaxf(rm, __shfl_xor(rm, 16));
        rm = fmaxf(rm, __shfl_xor(rm, 32));
        const float mnew  = fmaxf(m_i, rm);
        const float alpha = __expf(m_i - mnew);
        m_i = mnew;

        float ps = 0.f;
        #pragma unroll
        for (int ki = 0; ki < 4; ki++) {
            float p[4];
            #pragma unroll
            for (int r = 0; r < 4; r++) { p[r] = __expf(sv[ki][r] - mnew); ps += p[r]; }
            ushort4 pk;
            pk.x = f2bf(p[0]); pk.y = f2bf(p[1]); pk.z = f2bf(p[2]); pk.w = f2bf(p[3]);
            *(ushort4*)&Ps[(qr + l15) * 72 + ki * 16 + l16 * 4] = pk;
        }
        ps += __shfl_xor(ps, 16);
        ps += __shfl_xor(ps, 32);
        l_i = l_i * alpha + ps;
        #pragma unroll
        for (int mi = 0; mi < 4; mi++)
            #pragma unroll
            for (int r = 0; r < 4; r++) o4[mi][r] *= alpha;

        // O^T += V^T . P^T : A = Vst (swizzled), B = Ps (padded)
        const bf16x8 bP0 = *(const bf16x8*)&Ps[(qr + l15) * 72 + l16 * 8];
        const bf16x8 bP1 = *(const bf16x8*)&Ps[(qr + l15) * 72 + 32 + l16 * 8];
        #pragma unroll
        for (int mi = 0; mi < 4; mi++) {
            const int r = mi * 16 + l15;
            const bf16x8 aV0 = *(const bf16x8*)&Vst[r * 64 + sw0];
            const bf16x8 aV1 = *(const bf16x8*)&Vst[r * 64 + sw1];
            o4[mi] = __builtin_amdgcn_mfma_f32_16x16x32_bf16(aV0, bP0, o4[mi], 0, 0, 0);
            o4[mi] = __builtin_amdgcn_mfma_f32_16x16x32_bf16(aV1, bP1, o4[mi], 0, 0, 0);
        }
    }

    // write O: col q = qr+l15, rows d = mi*16 + l16*4 + r (packed 8B)
    const float inv = 1.f / l_i;
    #pragma unroll
    for (int mi = 0; mi < 4; mi++) {
        ushort4 ok;
        ok.x = f2bf(o4[mi][0] * inv); ok.y = f2bf(o4[mi][1] * inv);
        ok.z = f2bf(o4[mi][2] * inv); ok.w = f2bf(o4[mi][3] * inv);
        *(ushort4*)&z[(size_t)(b * SEQ + q0 + qr + l15) * DM + h * 64 + mi * 16 + l16 * 4] = ok;
    }
}

// ------------------------------------------------------------------
__global__ __launch_bounds__(256) void cast3_bf16(
    const float* __restrict__ a0, const float* __restrict__ a1, const float* __restrict__ a2,
    unsigned short* __restrict__ out)
{
    const float* src = blockIdx.z == 0 ? a0 : (blockIdx.z == 1 ? a1 : a2);
    const size_t i = ((size_t)blockIdx.x * 256 + threadIdx.x) * 4;
    const float4 v = *(const float4*)&src[i];
    ushort4 o; o.x = f2bf(v.x); o.y = f2bf(v.y); o.z = f2bf(v.z); o.w = f2bf(v.w);
    *(ushort4*)&out[(size_t)blockIdx.z * ((size_t)SEQ * 2 * DM) + i] = o;
}

// W[K][N] fp32 -> Wt[N][K] bf16 ; grid (N/64, K/64)
__global__ __launch_bounds__(256) void transpose_cast(
    const float* __restrict__ W, unsigned short* __restrict__ Wt, int K, int N)
{
    __shared__ float ts[64][65];
    const int n0 = blockIdx.x * 64, k0 = blockIdx.y * 64;
    const int t = threadIdx.x, r = t >> 4, c4 = (t & 15) * 4;
    #pragma unroll
    for (int i = 0; i < 4; i++) {
        const float4 v = *(const float4*)&W[(size_t)(k0 + r + i * 16) * N + n0 + c4];
        ts[r + i * 16][c4 + 0] = v.x; ts[r + i * 16][c4 + 1] = v.y;
        ts[r + i * 16][c4 + 2] = v.z; ts[r + i * 16][c4 + 3] = v.w;
    }
    __syncthreads();
    #pragma unroll
    for (int i = 0; i < 4; i++) {
        const int n = r + i * 16;
        ushort4 o;
        o.x = f2bf(ts[c4 + 0][n]); o.y = f2bf(ts[c4 + 1][n]);
        o.z = f2bf(ts[c4 + 2][n]); o.w = f2bf(ts[c4 + 3][n]);
        *(ushort4*)&Wt[(size_t)(n0 + n) * K + k0 + c4] = o;
    }
}

// vh bf16 [B*S][DM] -> vhT bf16 [(b*16+h)*64 + d][SEQ] ; grid (S/64, H, B)
__global__ __launch_bounds__(256) void transpose_v(
    const unsigned short* __restrict__ vh, unsigned short* __restrict__ vhT)
{
    __shared__ unsigned short ts[64][80];
    const int s0 = blockIdx.x * 64, h = blockIdx.y, b = blockIdx.z;
    const int t = threadIdx.x, rr = t >> 3, c8 = (t & 7) * 8;
    #pragma unroll
    for (int i = 0; i < 2; i++) {
        const int srow = rr + i * 32;
        *(uint4*)&ts[srow][c8] = *(const uint4*)&vh[(size_t)(b * SEQ + s0 + srow) * DM + h * 64 + c8];
    }
    __syncthreads();
    #pragma unroll
    for (int i = 0; i < 2; i++) {
        const int dr = rr + i * 32;
        ushort4 ov0, ov1;
        ov0.x = ts[c8 + 0][dr]; ov0.y = ts[c8 + 1][dr];
        ov0.z = ts[c8 + 2][dr]; ov0.w = ts[c8 + 3][dr];
        ov1.x = ts[c8 + 4][dr]; ov1.y = ts[c8 + 5][dr];
        ov1.z = ts[c8 + 6][dr]; ov1.w = ts[c8 + 7][dr];
        *(ushort4*)&vhT[(size_t)((b * 16 + h) * 64 + dr) * SEQ + s0 + c8] = ov0;
        *(ushort4*)&vhT[(size_t)((b * 16 + h) * 64 + dr) * SEQ + s0 + c8 + 4] = ov1;
    }
}

// ------------------------------------------------------------------
// LN + residual with optional second partial input (split-K sum).
// mode 0: out = LN(a+a2)*g+be + r (+bf16 copy) ; mode 1: out = LN(a+a2+r)*g+be
// ------------------------------------------------------------------
__global__ __launch_bounds__(256) void ln_res(
    const float* __restrict__ a, const float* __restrict__ a2,
    const float* __restrict__ r,
    const float* __restrict__ g, const float* __restrict__ be,
    float* __restrict__ out, unsigned short* __restrict__ outb, int mode)
{
    __shared__ float redls[8];
    const int row = blockIdx.x, t = threadIdx.x;
    const size_t base = (size_t)row * DM;

    float vals[4], s = 0.f, sq = 0.f;
    #pragma unroll
    for (int i = 0; i < 4; i++) {
        const int c = t + 256 * i;
        float x = a[base + c];
        if (a2) x += a2[base + c];
        if (mode == 1) x += r[base + c];
        vals[i] = x; s += x; sq += x * x;
    }
    #pragma unroll
    for (int off = 32; off > 0; off >>= 1) { s += __shfl_down(s, off); sq += __shfl_down(sq, off); }
    if ((t & 63) == 0) { redls[t >> 6] = s; redls[4 + (t >> 6)] = sq; }
    __syncthreads();
    s  = redls[0] + redls[1] + redls[2] + redls[3];
    sq = redls[4] + redls[5] + redls[6] + redls[7];

    const float mu  = s * (1.f / 1024.f);
    const float var = sq * (1.f / 1024.f) - mu * mu;
    const float rs  = rsqrtf(var + LNEPS);
    #pragma unroll
    for (int i = 0; i < 4; i++) {
        const int c = t + 256 * i;
        float y = (vals[i] - mu) * rs * g[c] + be[c];
        if (mode == 0) y += r[base + c];
        out[base + c] = y;
        if (outb) outb[base + c] = f2bf(y);
    }
}

// ------------------------------------------------------------------
extern "C" void kernel_launch(void* const* d_in, const int* in_sizes, int n_in,
                              void* d_out, int out_size, void* d_ws, size_t ws_size,
                              hipStream_t stream)
{
    const float* q    = (const float*)d_in[0];
    const float* k    = (const float*)d_in[1];
    const float* v    = (const float*)d_in[2];
    const float* mask = (const float*)d_in[4];
    const float* Wq   = (const float*)d_in[5];
    const float* Wk   = (const float*)d_in[6];
    const float* Wv   = (const float*)d_in[7];
    const float* Wd   = (const float*)d_in[8];
    const float* W1   = (const float*)d_in[9];
    const float* b1   = (const float*)d_in[10];
    const float* W2   = (const float*)d_in[11];
    const float* b2   = (const float*)d_in[12];
    const float* g1   = (const float*)d_in[13];
    const float* be1  = (const float*)d_in[14];
    const float* g2   = (const float*)d_in[15];
    const float* be2  = (const float*)d_in[16];
    float* out = (float*)d_out;

    char* WS = (char*)d_ws;
    const size_t MiB = 1u << 20;
    const size_t ND  = (size_t)4096 * 1024;

    unsigned short* qb  = (unsigned short*)(WS + 0);          // 24 MiB qb|kb|vb
    unsigned short* vhT = (unsigned short*)(WS + 0);          //  8 MiB (reuse)
    unsigned short* zb  = (unsigned short*)(WS + 8 * MiB);    //  8 MiB (reuse)
    unsigned short* xb  = (unsigned short*)(WS + 16 * MiB);   //  8 MiB (reuse)
    unsigned short* Wqt = (unsigned short*)(WS + 24 * MiB);   //  6 MiB WqT|WkT|WvT
    unsigned short* Wdt = (unsigned short*)(WS + 30 * MiB);   //  2 MiB
    unsigned short* W1t = (unsigned short*)(WS + 32 * MiB);   //  8 MiB
    unsigned short* W2t = (unsigned short*)(WS + 40 * MiB);   //  8 MiB
    unsigned short* qh  = (unsigned short*)(WS + 48 * MiB);   // 24 MiB qh|kh|vh
    float*          zd0 = (float*)(WS + 48 * MiB);            // 16 MiB (reuse qh|kh)
    float*          zd1 = (float*)(WS + 64 * MiB);            // 16 MiB (reuse vh+)
    float*          x   = (float*)(WS + 80 * MiB);            // 16 MiB
    unsigned short* h1  = (unsigned short*)(WS + 96 * MiB);   // 32 MiB
    float*          y0  = (float*)(WS + 48 * MiB);            // reuse zd
    float*          y1  = (float*)(WS + 64 * MiB);

    unsigned short* kh = qh + ND;
    unsigned short* vh = qh + 2 * ND;

    const dim3 blk(256);

    cast3_bf16<<<dim3(4096, 1, 3), blk, 0, stream>>>(q, k, v, qb);
    transpose_cast<<<dim3(16, 16), blk, 0, stream>>>(Wq, Wqt,                   1024, 1024);
    transpose_cast<<<dim3(16, 16), blk, 0, stream>>>(Wk, Wqt + 1024 * 1024,     1024, 1024);
    transpose_cast<<<dim3(16, 16), blk, 0, stream>>>(Wv, Wqt + 2 * 1024 * 1024, 1024, 1024);
    transpose_cast<<<dim3(16, 16), blk, 0, stream>>>(Wd, Wdt, 1024, 1024);
    transpose_cast<<<dim3(64, 16), blk, 0, stream>>>(W1, W1t, 1024, 4096);
    transpose_cast<<<dim3(16, 64), blk, 0, stream>>>(W2, W2t, 4096, 1024);

    // QKV projections (z = batch of 3)
    gemm_bf16<<<dim3(8, 32, 3), blk, 0, stream>>>(qb, Wqt, nullptr, qh,
        4096, 1024, 1024, 1024, 1024, ND, (size_t)1024 * 1024, ND, nullptr, 0);

    transpose_v<<<dim3(32, 16, 2), blk, 0, stream>>>(vh, vhT);

    attn_mfma<<<dim3(1024), blk, 0, stream>>>(qh, kh, vhT, mask, zb);

    // out-proj, split-K x2 -> zd0/zd1
    gemm_bf16<<<dim3(8, 32, 2), blk, 0, stream>>>(zb, Wdt, zd0, nullptr,
        4096, 1024, 512, 1024, 1024, 512, 512, ND, nullptr, 0);

    // LN1: x = LN(zd0+zd1) + q
    ln_res<<<dim3(4096), blk, 0, stream>>>(zd0, zd1, q, g1, be1, x, xb, 0);

    // FFN
    gemm_bf16<<<dim3(32, 32, 1), blk, 0, stream>>>(xb, W1t, nullptr, h1,
        4096, 4096, 1024, 1024, 1024, 0, 0, 0, b1, 2);
    gemm_bf16<<<dim3(8, 32, 2), blk, 0, stream>>>(h1, W2t, y0, nullptr,
        4096, 1024, 2048, 4096, 4096, 2048, 2048, ND, b2, 1);

    // LN2: out = LN(y0+y1+x)
    ln_res<<<dim3(4096), blk, 0, stream>>>(y0, y1, x, g2, be2, out, nullptr, 1);
}